// Round 3
// baseline (296.870 us; speedup 1.0000x reference)
//
#include <hip/hip_runtime.h>

#define N_NODES 100000
#define N_EDGES 3200000
#define BATCH 16384
#define MAX_SLOTS 32768

// Fixed-capacity per-slot scatter: degree of any node is ~Poisson(32);
// P(deg >= 128) ~ 5e-36, so CAP=128 cannot overflow for any realistic input.
#define CAP 128

// Workspace layout (byte offsets, 16B aligned). ws_size = 256 MiB.
#define OFF_SLOT      0          // 100000 u32 (i+1 for winners; garbage elsewhere; read only at pair nodes)
#define OFF_DEG       400000     // 100000 u32 edge-count per node (zeroed in k_flags)
#define OFF_DINV      800000     // 100000 f32
#define OFF_NODELIST  1200000    // 32768 ints (slot -> node, with duplicates)
#define OFF_SCOUNT    1331072    // 32768 ints per-slot edge counters (zeroed in k_flags)
#define OFF_WH        1462144    // bf16 w*dinv, 100000x64x2 B = 12.8 MB
#define OFF_BINS2     14262144   // per-slot src ids, 32768 x 128 x 4 B = 16 MB
#define OFF_EMB       31039360   // bf16 32768x64

__device__ __forceinline__ unsigned bfr(float f) {   // fp32 -> bf16 bits, RNE
    unsigned u = __float_as_uint(f);
    return (u + 0x7FFFu + ((u >> 16) & 1u)) >> 16;
}
__device__ __forceinline__ float bfx(unsigned h) {   // low 16 bits -> fp32
    return __uint_as_float(h << 16);
}

// Slot assignment + deg/scount clear, one kernel (grid covers N_NODES).
// slot[n] races to one winner; all writers of slot[n] have pairs[i]==n, so any
// winner is valid. Loser slots get empty bins + self-term-only emb, never read.
__global__ void k_flags(const int* __restrict__ pairs, unsigned* __restrict__ slot,
                        int* __restrict__ nodelist, unsigned* __restrict__ deg,
                        int* __restrict__ scount) {
    int i = blockIdx.x * blockDim.x + threadIdx.x;
    if (i < N_NODES) deg[i] = 0;
    if (i < 2 * BATCH) {
        int n = pairs[i];
        nodelist[i] = n;
        slot[n] = (unsigned)(i + 1);
        scount[i] = 0;
    }
}

// Certified needed-test: r=slot[d] valid iff (r-1)<32768 AND nodelist[r-1]==d.
// Both arrays are small (528 KB) -> L2-resident after first touch; empirically
// faster than an LDS bitmap (r2: bitmap ADDED 11us by loading the per-CU LDS pipe).
__device__ __forceinline__ int cert(int d, const unsigned* __restrict__ slot,
                                    const int* __restrict__ nodelist) {
    unsigned r = slot[d];
    unsigned idx = r - 1u;
    if (idx < (unsigned)MAX_SLOTS && nodelist[idx] == d) return (int)idx;
    return -1;
}

// Single edge pass, ZERO LDS. Degrees via fire-and-forget global atomics (no
// return value -> no latency chain, pipelined through L2). The r0-r2 LDS
// nibble-histogram structure (50 KB LDS, 256 fat blocks, all edges through one
// LDS pipe per CU) was the measured 40-78us rock; this replaces it with ~3.2M
// no-return atomic_adds + the already-present cert+scatter, at 32 waves/CU.
__global__ void k_edge(const int4* __restrict__ src4, const int4* __restrict__ dst4,
                       const unsigned* __restrict__ slot, const int* __restrict__ nodelist,
                       unsigned* __restrict__ deg, int* __restrict__ scount,
                       int* __restrict__ bins2) {
    const int NI4 = N_EDGES / 4;
    int i = blockIdx.x * blockDim.x + threadIdx.x;
    int stride = gridDim.x * blockDim.x;
    for (; i < NI4; i += stride) {
        int4 d = dst4[i];
        int4 s = src4[i];
        atomicAdd(&deg[d.x], 1u);
        atomicAdd(&deg[d.y], 1u);
        atomicAdd(&deg[d.z], 1u);
        atomicAdd(&deg[d.w], 1u);
        int t;
        t = cert(d.x, slot, nodelist);
        if (t >= 0) { int p = atomicAdd(&scount[t], 1); if (p < CAP) bins2[(t << 7) + p] = s.x; }
        t = cert(d.y, slot, nodelist);
        if (t >= 0) { int p = atomicAdd(&scount[t], 1); if (p < CAP) bins2[(t << 7) + p] = s.y; }
        t = cert(d.z, slot, nodelist);
        if (t >= 0) { int p = atomicAdd(&scount[t], 1); if (p < CAP) bins2[(t << 7) + p] = s.z; }
        t = cert(d.w, slot, nodelist);
        if (t >= 0) { int p = atomicAdd(&scount[t], 1); if (p < CAP) bins2[(t << 7) + p] = s.w; }
    }
}

// Pure stream: read w (25.6 MB) + deg (0.4 MB), write wh bf16 (12.8 MB) + dinv
// (0.4 MB). One thread per uint4 output (8 dims); 8 threads share a node ->
// redundant rsqrt is free, deg load merges in L2.
__global__ void k_mid(const unsigned* __restrict__ deg, const float4* __restrict__ w4,
                      float* __restrict__ dinv, uint4* __restrict__ wh4) {
    int k = blockIdx.x * blockDim.x + threadIdx.x;
    if (k >= N_NODES * 8) return;
    int n = k >> 3;
    float d = rsqrtf((float)deg[n] + 1.0f);
    float4 va = w4[k * 2];
    float4 vb = w4[k * 2 + 1];
    uint4 o;
    o.x = bfr(va.x * d) | (bfr(va.y * d) << 16);
    o.y = bfr(va.z * d) | (bfr(va.w * d) << 16);
    o.z = bfr(vb.x * d) | (bfr(vb.y * d) << 16);
    o.w = bfr(vb.z * d) | (bfr(vb.w * d) << 16);
    wh4[k] = o;
    if ((k & 7) == 0) dinv[n] = d;
}

// One wave per slot (empty loser slots trivial), 8 rows per instruction:
// lane = (rg = lane>>3) x (dp = lane&7), uint4 loads. f64 accumulation keeps
// the race-ordered bins2 sum bit-stable across runs.
__global__ void k_gather(const int* __restrict__ nodelist, const int* __restrict__ scount,
                         const int* __restrict__ bins2, const uint4* __restrict__ wh4,
                         const float* __restrict__ dinv, const float4* __restrict__ bias4,
                         uint4* __restrict__ emb4) {
    int s = (blockIdx.x * blockDim.x + threadIdx.x) >> 6;
    int lane = threadIdx.x & 63;
    int rg = lane >> 3, dp = lane & 7;
    int cnt = scount[s];
    if (cnt > CAP) cnt = CAP;
    const int* bp = bins2 + (s << 7);
    double a0 = 0., a1 = 0., a2 = 0., a3 = 0., a4 = 0., a5 = 0., a6 = 0., a7 = 0.;
    int j = 0;
    for (; j + 16 <= cnt; j += 16) {
        int e0 = bp[j + rg];
        int e1 = bp[j + 8 + rg];
        uint4 oa = wh4[(e0 << 3) + dp];
        uint4 ob = wh4[(e1 << 3) + dp];
        a0 += (double)(bfx(oa.x) + bfx(ob.x));
        a1 += (double)(bfx(oa.x >> 16) + bfx(ob.x >> 16));
        a2 += (double)(bfx(oa.y) + bfx(ob.y));
        a3 += (double)(bfx(oa.y >> 16) + bfx(ob.y >> 16));
        a4 += (double)(bfx(oa.z) + bfx(ob.z));
        a5 += (double)(bfx(oa.z >> 16) + bfx(ob.z >> 16));
        a6 += (double)(bfx(oa.w) + bfx(ob.w));
        a7 += (double)(bfx(oa.w >> 16) + bfx(ob.w >> 16));
    }
    for (; j < cnt; j += 8) {
        if (rg < cnt - j) {
            int e0 = bp[j + rg];
            uint4 oa = wh4[(e0 << 3) + dp];
            a0 += (double)bfx(oa.x); a1 += (double)bfx(oa.x >> 16);
            a2 += (double)bfx(oa.y); a3 += (double)bfx(oa.y >> 16);
            a4 += (double)bfx(oa.z); a5 += (double)bfx(oa.z >> 16);
            a6 += (double)bfx(oa.w); a7 += (double)bfx(oa.w >> 16);
        }
    }
#pragma unroll
    for (int m = 8; m <= 32; m <<= 1) {
        a0 += __shfl_xor(a0, m, 64); a1 += __shfl_xor(a1, m, 64);
        a2 += __shfl_xor(a2, m, 64); a3 += __shfl_xor(a3, m, 64);
        a4 += __shfl_xor(a4, m, 64); a5 += __shfl_xor(a5, m, 64);
        a6 += __shfl_xor(a6, m, 64); a7 += __shfl_xor(a7, m, 64);
    }
    if (rg == 0) {
        int n = nodelist[s];
        float dn = dinv[n];
        uint4 u = wh4[(n << 3) + dp];
        float4 b0 = bias4[dp * 2], b1 = bias4[dp * 2 + 1];
        float r0 = ((float)a0 + bfx(u.x)) * dn + b0.x;
        float r1 = ((float)a1 + bfx(u.x >> 16)) * dn + b0.y;
        float r2 = ((float)a2 + bfx(u.y)) * dn + b0.z;
        float r3 = ((float)a3 + bfx(u.y >> 16)) * dn + b0.w;
        float r4 = ((float)a4 + bfx(u.z)) * dn + b1.x;
        float r5 = ((float)a5 + bfx(u.z >> 16)) * dn + b1.y;
        float r6 = ((float)a6 + bfx(u.w)) * dn + b1.z;
        float r7 = ((float)a7 + bfx(u.w >> 16)) * dn + b1.w;
        uint4 o;
        o.x = bfr(r0) | (bfr(r1) << 16);
        o.y = bfr(r2) | (bfr(r3) << 16);
        o.z = bfr(r4) | (bfr(r5) << 16);
        o.w = bfr(r6) | (bfr(r7) << 16);
        emb4[(s << 3) + dp] = o;
    }
}

// Four pairs per wave (16 lanes each), uint2 loads (4 dims/lane). slot[a] is
// always a winner id for pair nodes (written this launch by k_flags).
__global__ void k_final(const int* __restrict__ pairs, const unsigned* __restrict__ slot,
                        const uint2* __restrict__ emb2, const float* __restrict__ lw,
                        const float* __restrict__ lb, float* __restrict__ out) {
    int p = (blockIdx.x * blockDim.x + threadIdx.x) >> 4;
    int li = threadIdx.x & 15;
    if (p >= BATCH) return;
    int a = pairs[p * 2], b = pairs[p * 2 + 1];
    int sa = (int)slot[a] - 1;
    int sb = (int)slot[b] - 1;
    uint2 ua = emb2[(sa << 4) + li];
    uint2 ub = emb2[(sb << 4) + li];
    float prod = bfx(ua.x) * bfx(ub.x) + bfx(ua.x >> 16) * bfx(ub.x >> 16)
               + bfx(ua.y) * bfx(ub.y) + bfx(ua.y >> 16) * bfx(ub.y >> 16);
#pragma unroll
    for (int m = 1; m <= 8; m <<= 1) prod += __shfl_xor(prod, m, 64);
    if (li == 0) out[p] = lw[a] + lw[b] + lb[0] + prod;
}

extern "C" void kernel_launch(void* const* d_in, const int* in_sizes, int n_in,
                              void* d_out, int out_size, void* d_ws, size_t ws_size,
                              hipStream_t stream) {
    const float* gcn_weight    = (const float*)d_in[0];
    const float* gcn_bias      = (const float*)d_in[1];
    const float* linear_weight = (const float*)d_in[2];
    const float* linear_bias   = (const float*)d_in[3];
    const int*   edge_index    = (const int*)d_in[4];
    const int*   pairs         = (const int*)d_in[5];
    float* out = (float*)d_out;

    char* ws = (char*)d_ws;
    unsigned* slot      = (unsigned*)(ws + OFF_SLOT);
    unsigned* deg       = (unsigned*)(ws + OFF_DEG);
    float*    dinv      = (float*)   (ws + OFF_DINV);
    int*      nodelist  = (int*)     (ws + OFF_NODELIST);
    int*      scount    = (int*)     (ws + OFF_SCOUNT);
    uint4*    wh4       = (uint4*)   (ws + OFF_WH);
    int*      bins2     = (int*)     (ws + OFF_BINS2);
    uint4*    emb4      = (uint4*)   (ws + OFF_EMB);
    uint2*    emb2      = (uint2*)   (ws + OFF_EMB);

    const int* src_arr = edge_index;
    const int* dst_arr = edge_index + N_EDGES;

    k_flags<<<196, 512, 0, stream>>>(pairs, slot, nodelist, deg, scount);
    k_edge<<<2048, 256, 0, stream>>>((const int4*)src_arr, (const int4*)dst_arr,
                                     slot, nodelist, deg, scount, bins2);
    k_mid<<<(N_NODES * 8 + 1023) / 1024, 1024, 0, stream>>>(deg, (const float4*)gcn_weight,
                                                            dinv, wh4);
    k_gather<<<MAX_SLOTS / 4, 256, 0, stream>>>(nodelist, scount, bins2, wh4,
                                                dinv, (const float4*)gcn_bias, emb4);
    k_final<<<1024, 256, 0, stream>>>(pairs, slot, emb2, linear_weight, linear_bias, out);
}

// Round 4
// 163.132 us; speedup vs baseline: 1.8198x; 1.8198x over previous
//
#include <hip/hip_runtime.h>

#define N_NODES 100000
#define N_EDGES 3200000
#define BATCH 16384
#define MAX_SLOTS 32768

// Nibble-packed degree histogram: 100K nodes x 4 bit = 50 KB LDS.
#define NW 12500       // words (8 nodes/word)
#define SLICES 256
#define EPS2 12500     // edges per slice
#define I4PS2 3125

// Bucket machinery: 256 buckets x 128 slots.
#define NBUCK 256
#define BCAP 8192      // entries per bucket region; mean fill 3513, sigma~140 -> +33 sigma
#define BCAP_SH 13
#define EBCAP 4608     // per-block LDS staging; mean 3513, sigma~50 -> +22 sigma

// Workspace layout (byte offsets, 16B aligned). ws_size = 256 MiB.
#define OFF_SLOT      0          // 100000 u32 (i+1 for winners; garbage elsewhere)
#define OFF_DINV      400000     // 100000 f32
#define OFF_NODELIST  800000     // 32768 ints (slot -> node, with duplicates)
#define OFF_GCUR      931072     // 256 u32 bucket cursors (init b<<13 in k_flags)
#define OFF_PARTIALS  932096     // 256 x 12500 words = 12.8 MB nibble degree counts
#define OFF_WH        13732096   // bf16 w*dinv, 100000x64x2 B = 12.8 MB
#define OFF_BINS      26532096   // packed (slot<<17|src), 256 buckets x 8192 x 4 B = 8 MB
#define OFF_EMB       34920704   // bf16 32768x64

__device__ __forceinline__ unsigned bfr(float f) {   // fp32 -> bf16 bits, RNE
    unsigned u = __float_as_uint(f);
    return (u + 0x7FFFu + ((u >> 16) & 1u)) >> 16;
}
__device__ __forceinline__ float bfx(unsigned h) {   // low 16 bits -> fp32
    return __uint_as_float(h << 16);
}

// Slot assignment + bucket-cursor init. slot[n] races to one winner; all
// writers of slot[n] have pairs[i]==n, so any winner is valid. Loser slots get
// zero edges (cert certifies only the winner) and a self-term-only emb that
// k_final never reads.
__global__ void k_flags(const int* __restrict__ pairs, unsigned* __restrict__ slot,
                        int* __restrict__ nodelist, unsigned* __restrict__ gcur) {
    int i = blockIdx.x * blockDim.x + threadIdx.x;
    if (i < NBUCK) gcur[i] = (unsigned)(i << BCAP_SH);
    if (i < 2 * BATCH) {
        int n = pairs[i];
        nodelist[i] = n;
        slot[n] = (unsigned)(i + 1);
    }
}

// Certified needed-test: r=slot[d] valid iff (r-1)<32768 AND nodelist[r-1]==d.
// Both arrays small (528 KB) -> L2-resident; measured fine inside r0's k_hist.
__device__ __forceinline__ int cert(int d, const unsigned* __restrict__ slot,
                                    const int* __restrict__ nodelist) {
    unsigned r = slot[d];
    unsigned idx = r - 1u;
    if (idx < (unsigned)MAX_SLOTS && nodelist[idx] == d) return (int)idx;
    return -1;
}

// ONE edge pass: nibble degree histogram (measured-good r0 structure) + cert +
// LDS-staged compact scatter. NO per-edge global atomics (r1/r3 lesson: each
// device-scope global atomic costs ~43-53 B of EA traffic + memory-side
// latency; 0.9M of them = +25us, 4.1M = 184us). Space reservation is one
// global atomic per (block,bucket): 65K total ~ 3 MB EA. Staged entries flush
// as contiguous per-bucket runs -> bins writes are compact.
__global__ void k_hist(const int* __restrict__ src, const int* __restrict__ dst,
                       const unsigned* __restrict__ slot, const int* __restrict__ nodelist,
                       unsigned* __restrict__ partials, unsigned* __restrict__ gcur,
                       unsigned* __restrict__ bins) {
    __shared__ unsigned h[NW];          // 50 KB
    __shared__ unsigned ebuf[EBCAP];    // 18 KB staged (slot<<17|src)
    __shared__ int lc[NBUCK];
    __shared__ int base[NBUCK];
    __shared__ int ecnt;
    int g = blockIdx.x;
    int tid = threadIdx.x;
    int lane = tid & 63;
    for (int i = tid; i < NW; i += 512) h[i] = 0;
    if (tid < NBUCK) lc[tid] = 0;
    if (tid == 0) ecnt = 0;
    __syncthreads();
    const int4* d4 = (const int4*)(dst + g * EPS2);
    const int4* s4 = (const int4*)(src + g * EPS2);
    for (int i = tid; i < I4PS2; i += 512) {
        int4 v = d4[i];
        int4 s = s4[i];
        atomicAdd(&h[v.x >> 3], 1u << ((v.x & 7) << 2));
        atomicAdd(&h[v.y >> 3], 1u << ((v.y & 7) << 2));
        atomicAdd(&h[v.z >> 3], 1u << ((v.z & 7) << 2));
        atomicAdd(&h[v.w >> 3], 1u << ((v.w & 7) << 2));
        // Wave-aggregated staging: 1 ecnt atomic per wave per component, not
        // per thread (single-address LDS RMWs serialize).
#define STAGE(dc, sc)                                                          \
        {                                                                      \
            int t = cert(dc, slot, nodelist);                                  \
            unsigned long long mk = __ballot(t >= 0);                          \
            int bs = 0;                                                        \
            if (lane == 0) bs = atomicAdd(&ecnt, (int)__popcll(mk));           \
            bs = __shfl(bs, 0, 64);                                            \
            if (t >= 0) {                                                      \
                int off = bs + (int)__popcll(mk & ((1ull << lane) - 1ull));    \
                if (off < EBCAP) {                                             \
                    ebuf[off] = ((unsigned)t << 17) | (unsigned)(sc);          \
                    atomicAdd(&lc[t >> 7], 1);                                 \
                }                                                              \
            }                                                                  \
        }
        STAGE(v.x, s.x)
        STAGE(v.y, s.y)
        STAGE(v.z, s.z)
        STAGE(v.w, s.w)
#undef STAGE
    }
    __syncthreads();
    unsigned* outp = partials + (unsigned)g * NW;
    for (int i = tid; i < NW; i += 512) outp[i] = h[i];
    if (tid < NBUCK) {
        base[tid] = (int)atomicAdd(&gcur[tid], (unsigned)lc[tid]);
        lc[tid] = 0;                      // reuse as flush rank cursor
    }
    __syncthreads();
    int ne = ecnt;
    if (ne > EBCAP) ne = EBCAP;
    for (int j = tid; j < ne; j += 512) {
        unsigned e = ebuf[j];
        int b = (int)(e >> 24);           // slot>>7
        int r = atomicAdd(&lc[b], 1);
        unsigned pos = (unsigned)base[b] + (unsigned)r;
        if (pos < (unsigned)((b + 1) << BCAP_SH)) bins[pos] = e;
    }
}

// Reduce nibble partials -> dinv, and convert w rows to bf16 wh = w*dinv.
__global__ void k_mid(const unsigned* __restrict__ partials, const float4* __restrict__ w4,
                      float* __restrict__ dinv, uint4* __restrict__ wh4) {
    __shared__ unsigned pA[256], pB[256], pC[256], pD[256];
    __shared__ float sdinv[256];
    int blk = blockIdx.x;
    int wi = threadIdx.x & 31, sg = threadIdx.x >> 5;    // word-in-block, slice-group
    int w = blk * 32 + wi;
    unsigned A = 0, B = 0, C = 0, D = 0;
    if (w < NW) {
        const unsigned* q = partials + w;
#pragma unroll
        for (int ch = 0; ch < 2; ++ch) {                 // 2 chunks x 16 slices
            unsigned x = 0, y = 0;
#pragma unroll
            for (int k = 0; k < 16; ++k) {
                unsigned v = q[(unsigned)(sg * 32 + ch * 16 + k) * NW];
                x += v & 0x0F0F0F0Fu;
                y += (v >> 4) & 0x0F0F0F0Fu;
            }
            A += x & 0x00FF00FFu;          // (n0, n4)
            B += (x >> 8) & 0x00FF00FFu;   // (n2, n6)
            C += y & 0x00FF00FFu;          // (n1, n5)
            D += (y >> 8) & 0x00FF00FFu;   // (n3, n7)
        }
    }
    pA[threadIdx.x] = A; pB[threadIdx.x] = B; pC[threadIdx.x] = C; pD[threadIdx.x] = D;
    __syncthreads();
    if (threadIdx.x < 32 && w < NW) {
        unsigned sA = 0, sB = 0, sC = 0, sD = 0;
#pragma unroll
        for (int k = 0; k < 8; ++k) {
            sA += pA[k * 32 + wi]; sB += pB[k * 32 + wi];
            sC += pC[k * 32 + wi]; sD += pD[k * 32 + wi];
        }
        float4 d0, d1;
        d0.x = rsqrtf((float)(sA & 0xFFFFu) + 1.0f);
        d0.y = rsqrtf((float)(sC & 0xFFFFu) + 1.0f);
        d0.z = rsqrtf((float)(sB & 0xFFFFu) + 1.0f);
        d0.w = rsqrtf((float)(sD & 0xFFFFu) + 1.0f);
        d1.x = rsqrtf((float)(sA >> 16) + 1.0f);
        d1.y = rsqrtf((float)(sC >> 16) + 1.0f);
        d1.z = rsqrtf((float)(sB >> 16) + 1.0f);
        d1.w = rsqrtf((float)(sD >> 16) + 1.0f);
        ((float4*)dinv)[w * 2] = d0;
        ((float4*)dinv)[w * 2 + 1] = d1;
        int lb = wi * 8;
        sdinv[lb + 0] = d0.x; sdinv[lb + 1] = d0.y; sdinv[lb + 2] = d0.z; sdinv[lb + 3] = d0.w;
        sdinv[lb + 4] = d1.x; sdinv[lb + 5] = d1.y; sdinv[lb + 6] = d1.z; sdinv[lb + 7] = d1.w;
    }
    __syncthreads();
#pragma unroll
    for (int it = 0; it < 8; ++it) {
        int k = blk * 2048 + it * 256 + threadIdx.x;   // uint4 index (8 dims); node = k>>3
        if (k < N_NODES * 8) {
            float4 va = w4[k * 2];
            float4 vb = w4[k * 2 + 1];
            float d = sdinv[(k >> 3) - blk * 256];
            uint4 o;
            o.x = bfr(va.x * d) | (bfr(va.y * d) << 16);
            o.y = bfr(va.z * d) | (bfr(va.w * d) << 16);
            o.z = bfr(vb.x * d) | (bfr(vb.y * d) << 16);
            o.w = bfr(vb.z * d) | (bfr(vb.w * d) << 16);
            wh4[k] = o;
        }
    }
}

// Fused counting-sort + gather (replaces k_bsort + k_gather, deleting the
// bins2 round-trip). 4 blocks per bucket each redundantly sort the bucket's
// ~3.5K entries in LDS (cheap, L2-hot) then gather 32 of its 128 slots.
// 8 waves x 4 slots; per slot the wave does the measured k_gather layout
// (rg = lane>>3 rows x dp = lane&7 dims, uint4 loads, f64 accumulate for
// bit-stable race-ordered sums).
__global__ void k_gfuse(const unsigned* __restrict__ gcur, const unsigned* __restrict__ bins,
                        const int* __restrict__ nodelist, const uint4* __restrict__ wh4,
                        const float* __restrict__ dinv, const float4* __restrict__ bias4,
                        uint4* __restrict__ emb4) {
    __shared__ unsigned ebuf2[BCAP];    // 32 KB sorted src ids
    __shared__ int lc[128], st[128];
    int b = blockIdx.x >> 2;
    int qt = blockIdx.x & 3;
    int tid = threadIdx.x;
    int cnt = (int)(gcur[b] - (unsigned)(b << BCAP_SH));
    if (cnt > BCAP) cnt = BCAP;
    const unsigned* bp = bins + ((unsigned)b << BCAP_SH);
    if (tid < 128) lc[tid] = 0;
    __syncthreads();
    for (int j = tid; j < cnt; j += 512) atomicAdd(&lc[(bp[j] >> 17) & 127], 1);
    __syncthreads();
    if (tid < 128) st[tid] = lc[tid];
    __syncthreads();
    for (int off = 1; off < 128; off <<= 1) {
        int v = (tid < 128 && tid >= off) ? st[tid - off] : 0;
        __syncthreads();
        if (tid < 128) st[tid] += v;
        __syncthreads();
    }
    if (tid < 128) {
        st[tid] -= lc[tid];               // exclusive start (preserved)
        lc[tid] = st[tid];                // scatter cursor; final value = end
    }
    __syncthreads();
    for (int j = tid; j < cnt; j += 512) {
        unsigned e = bp[j];
        int r = atomicAdd(&lc[(e >> 17) & 127], 1);
        ebuf2[r] = e & 0x1FFFFu;
    }
    __syncthreads();
    int wave = tid >> 6, lane = tid & 63;
    int rg = lane >> 3, dp = lane & 7;
#pragma unroll
    for (int q = 0; q < 4; ++q) {
        int sl = qt * 32 + wave * 4 + q;
        int s0 = st[sl];
        int cn = lc[sl] - s0;
        double a0 = 0., a1 = 0., a2 = 0., a3 = 0., a4 = 0., a5 = 0., a6 = 0., a7 = 0.;
        int j = 0;
        for (; j + 16 <= cn; j += 16) {
            int e0 = (int)ebuf2[s0 + j + rg];
            int e1 = (int)ebuf2[s0 + j + 8 + rg];
            uint4 oa = wh4[(e0 << 3) + dp];
            uint4 ob = wh4[(e1 << 3) + dp];
            a0 += (double)(bfx(oa.x) + bfx(ob.x));
            a1 += (double)(bfx(oa.x >> 16) + bfx(ob.x >> 16));
            a2 += (double)(bfx(oa.y) + bfx(ob.y));
            a3 += (double)(bfx(oa.y >> 16) + bfx(ob.y >> 16));
            a4 += (double)(bfx(oa.z) + bfx(ob.z));
            a5 += (double)(bfx(oa.z >> 16) + bfx(ob.z >> 16));
            a6 += (double)(bfx(oa.w) + bfx(ob.w));
            a7 += (double)(bfx(oa.w >> 16) + bfx(ob.w >> 16));
        }
        for (; j < cn; j += 8) {
            if (rg < cn - j) {
                int e0 = (int)ebuf2[s0 + j + rg];
                uint4 oa = wh4[(e0 << 3) + dp];
                a0 += (double)bfx(oa.x); a1 += (double)bfx(oa.x >> 16);
                a2 += (double)bfx(oa.y); a3 += (double)bfx(oa.y >> 16);
                a4 += (double)bfx(oa.z); a5 += (double)bfx(oa.z >> 16);
                a6 += (double)bfx(oa.w); a7 += (double)bfx(oa.w >> 16);
            }
        }
#pragma unroll
        for (int m = 8; m <= 32; m <<= 1) {
            a0 += __shfl_xor(a0, m, 64); a1 += __shfl_xor(a1, m, 64);
            a2 += __shfl_xor(a2, m, 64); a3 += __shfl_xor(a3, m, 64);
            a4 += __shfl_xor(a4, m, 64); a5 += __shfl_xor(a5, m, 64);
            a6 += __shfl_xor(a6, m, 64); a7 += __shfl_xor(a7, m, 64);
        }
        if (rg == 0) {
            int gslot = (b << 7) + sl;
            int n = nodelist[gslot];
            float dn = dinv[n];
            uint4 u = wh4[(n << 3) + dp];
            float4 b0 = bias4[dp * 2], b1 = bias4[dp * 2 + 1];
            float r0 = ((float)a0 + bfx(u.x)) * dn + b0.x;
            float r1 = ((float)a1 + bfx(u.x >> 16)) * dn + b0.y;
            float r2 = ((float)a2 + bfx(u.y)) * dn + b0.z;
            float r3 = ((float)a3 + bfx(u.y >> 16)) * dn + b0.w;
            float r4 = ((float)a4 + bfx(u.z)) * dn + b1.x;
            float r5 = ((float)a5 + bfx(u.z >> 16)) * dn + b1.y;
            float r6 = ((float)a6 + bfx(u.w)) * dn + b1.z;
            float r7 = ((float)a7 + bfx(u.w >> 16)) * dn + b1.w;
            uint4 o;
            o.x = bfr(r0) | (bfr(r1) << 16);
            o.y = bfr(r2) | (bfr(r3) << 16);
            o.z = bfr(r4) | (bfr(r5) << 16);
            o.w = bfr(r6) | (bfr(r7) << 16);
            emb4[(gslot << 3) + dp] = o;
        }
    }
}

// Four pairs per wave (16 lanes each), uint2 loads (4 dims/lane). slot[a] is
// always a winner id for pair nodes (written this launch by k_flags).
__global__ void k_final(const int* __restrict__ pairs, const unsigned* __restrict__ slot,
                        const uint2* __restrict__ emb2, const float* __restrict__ lw,
                        const float* __restrict__ lb, float* __restrict__ out) {
    int p = (blockIdx.x * blockDim.x + threadIdx.x) >> 4;
    int li = threadIdx.x & 15;
    if (p >= BATCH) return;
    int a = pairs[p * 2], b = pairs[p * 2 + 1];
    int sa = (int)slot[a] - 1;
    int sb = (int)slot[b] - 1;
    uint2 ua = emb2[(sa << 4) + li];
    uint2 ub = emb2[(sb << 4) + li];
    float prod = bfx(ua.x) * bfx(ub.x) + bfx(ua.x >> 16) * bfx(ub.x >> 16)
               + bfx(ua.y) * bfx(ub.y) + bfx(ua.y >> 16) * bfx(ub.y >> 16);
#pragma unroll
    for (int m = 1; m <= 8; m <<= 1) prod += __shfl_xor(prod, m, 64);
    if (li == 0) out[p] = lw[a] + lw[b] + lb[0] + prod;
}

extern "C" void kernel_launch(void* const* d_in, const int* in_sizes, int n_in,
                              void* d_out, int out_size, void* d_ws, size_t ws_size,
                              hipStream_t stream) {
    const float* gcn_weight    = (const float*)d_in[0];
    const float* gcn_bias      = (const float*)d_in[1];
    const float* linear_weight = (const float*)d_in[2];
    const float* linear_bias   = (const float*)d_in[3];
    const int*   edge_index    = (const int*)d_in[4];
    const int*   pairs         = (const int*)d_in[5];
    float* out = (float*)d_out;

    char* ws = (char*)d_ws;
    unsigned* slot      = (unsigned*)(ws + OFF_SLOT);
    float*    dinv      = (float*)   (ws + OFF_DINV);
    int*      nodelist  = (int*)     (ws + OFF_NODELIST);
    unsigned* gcur      = (unsigned*)(ws + OFF_GCUR);
    unsigned* partials  = (unsigned*)(ws + OFF_PARTIALS);
    uint4*    wh4       = (uint4*)   (ws + OFF_WH);
    unsigned* bins      = (unsigned*)(ws + OFF_BINS);
    uint4*    emb4      = (uint4*)   (ws + OFF_EMB);
    uint2*    emb2      = (uint2*)   (ws + OFF_EMB);

    const int* src_arr = edge_index;
    const int* dst_arr = edge_index + N_EDGES;

    k_flags<<<64, 512, 0, stream>>>(pairs, slot, nodelist, gcur);
    k_hist<<<SLICES, 512, 0, stream>>>(src_arr, dst_arr, slot, nodelist,
                                       partials, gcur, bins);
    k_mid<<<391, 256, 0, stream>>>(partials, (const float4*)gcn_weight, dinv, wh4);
    k_gfuse<<<NBUCK * 4, 512, 0, stream>>>(gcur, bins, nodelist, wh4,
                                           dinv, (const float4*)gcn_bias, emb4);
    k_final<<<1024, 256, 0, stream>>>(pairs, slot, emb2, linear_weight, linear_bias, out);
}